// Round 7
// baseline (358.240 us; speedup 1.0000x reference)
//
#include <hip/hip_runtime.h>

// USMSharp R7: separable Gaussian, bf16 intermediates, barrier-free, light waves.
// K1 hblur8(img f32)->A bf16 ; K2 vblur5(A) -> r=img-blur bf16
// K3 hblur8(mask(|r|*255>10))->Bh bf16 (aliases A) ; K4 vblur5(Bh)+blend->out.
// R7: TV=5 vblur (2430 blocks), 8-out streaming hblur (6076 blocks), LB(256,8).

#define W 1920
#define H 1080
#define NP 6
#define PLANE (H * W)
#define TOT (NP * PLANE)
#define R 25
#define KS 51
#define TV 5                      // rows per thread in vblur
#define NXT 15                    // x tiles (128 cols)
#define NYT 27                    // y tiles (40 rows)
#define WU_TOTAL (NXT * NYT * NP)         // 2430
#define WU_PER_XCD ((WU_TOTAL + 7) / 8)   // 304
#define NROWS (H * NP)            // 6480
#define ICH 232                   // interior chunks per row (4..235)
#define NI (NROWS * ICH)
#define NBI ((NI + 255) / 256)    // 5873
#define NB (NROWS * 8)            // boundary chunks 0..3, 236..239
#define NBB ((NB + 255) / 256)    // 203

__device__ __forceinline__ int reflect_idx(int i, int n) {
    if (i < 0) i = -i;
    if (i >= n) i = 2 * n - 2 - i;
    return i;
}
__device__ __forceinline__ float bf2f(unsigned short u) {
    return __uint_as_float(((unsigned int)u) << 16);
}
__device__ __forceinline__ unsigned short f2bf(float f) {  // RNE
    unsigned int x = __float_as_uint(f);
    return (unsigned short)((x + 0x7FFFu + ((x >> 16) & 1u)) >> 16);
}
__device__ __forceinline__ float maskf(float f) {
    return (fabsf(f) * 255.f > 10.f) ? 1.f : 0.f;
}

__global__ void compute_k1(const float* __restrict__ k2d, float* __restrict__ k1) {
    int t = threadIdx.x;
    if (t < KS) {
        float s = 0.f;
        for (int j = 0; j < KS; ++j) s += k2d[t * KS + j];
        k1[t] = s;
    }
}

// acc[o] = sum_k k1[k]*x[c0+o-25+k], o in [0,8). window w[i]=x[c0-32+i], i in [0,72)
// element i contributes to o in [max(0,i-57), min(7,i-7)]
#define CONTRIB8(P, VV)                                                  \
    {                                                                    \
        const int _p = (P);                                              \
        if (_p >= 7 && _p <= 64) {                                       \
            const int _olo = (_p - 57 > 0) ? _p - 57 : 0;                \
            const int _ohi = (_p - 7 < 7) ? _p - 7 : 7;                  \
            _Pragma("unroll") for (int o = _olo; o <= _ohi; ++o)         \
                acc[o] += k1g[_p - 7 - o] * (VV);                        \
        }                                                                \
    }

template <bool MASK>
__global__ __launch_bounds__(256, 8) void hblur8(const void* __restrict__ inv,
                                                 unsigned short* __restrict__ out,
                                                 const float* __restrict__ k1g) {
    const int b = blockIdx.x;
    float acc[8];
#pragma unroll
    for (int o = 0; o < 8; ++o) acc[o] = 0.f;
    int row, c0;
    if (b < NBI) {  // interior: chunks 4..235, aligned streaming loads
        const int t = b * 256 + threadIdx.x;
        if (t >= NI) return;
        row = t / ICH;
        c0 = (4 + (t - row * ICH)) * 8;
        if constexpr (!MASK) {
            const float* rin = (const float*)inv + (size_t)row * W;
#pragma unroll
            for (int i = 0; i < 18; ++i) {
                float4 v = *(const float4*)(rin + c0 - 32 + 4 * i);
                CONTRIB8(4 * i + 0, v.x);
                CONTRIB8(4 * i + 1, v.y);
                CONTRIB8(4 * i + 2, v.z);
                CONTRIB8(4 * i + 3, v.w);
            }
        } else {
            const unsigned short* rin = (const unsigned short*)inv + (size_t)row * W;
#pragma unroll
            for (int i = 0; i < 9; ++i) {
                uint4 u = *(const uint4*)(rin + c0 - 32 + 8 * i);
#pragma unroll
                for (int h = 0; h < 4; ++h) {
                    const unsigned int c = (h == 0) ? u.x : (h == 1) ? u.y : (h == 2) ? u.z : u.w;
                    CONTRIB8(8 * i + 2 * h + 0, maskf(__uint_as_float(c << 16)));
                    CONTRIB8(8 * i + 2 * h + 1, maskf(__uint_as_float(c & 0xffff0000u)));
                }
            }
        }
    } else {  // boundary: chunks 0..3 / 236..239, scalar reflect loads
        const int t = (b - NBI) * 256 + threadIdx.x;
        if (t >= NB) return;
        row = t >> 3;
        const int q = t & 7;
        c0 = ((q < 4) ? q : q + 232) * 8;
        if constexpr (!MASK) {
            const float* rin = (const float*)inv + (size_t)row * W;
#pragma unroll
            for (int i = 7; i <= 64; ++i) CONTRIB8(i, rin[reflect_idx(c0 - 32 + i, W)]);
        } else {
            const unsigned short* rin = (const unsigned short*)inv + (size_t)row * W;
#pragma unroll
            for (int i = 7; i <= 64; ++i)
                CONTRIB8(i, maskf(bf2f(rin[reflect_idx(c0 - 32 + i, W)])));
        }
    }
    uint4 o0;
    o0.x = (unsigned int)f2bf(acc[0]) | ((unsigned int)f2bf(acc[1]) << 16);
    o0.y = (unsigned int)f2bf(acc[2]) | ((unsigned int)f2bf(acc[3]) << 16);
    o0.z = (unsigned int)f2bf(acc[4]) | ((unsigned int)f2bf(acc[5]) << 16);
    o0.w = (unsigned int)f2bf(acc[6]) | ((unsigned int)f2bf(acc[7]) << 16);
    *(uint4*)(out + (size_t)row * W + c0) = o0;
}

// ---- vertical conv: register rolling, 5 rows x 4 cols per thread -----------
__device__ __forceinline__ bool decode_wu(int lin, int& p, int& yt, int& xt) {
    int c = lin & 7, j = lin >> 3;
    int wu = c * WU_PER_XCD + j;   // XCD c owns a y-contiguous strip; xt innermost
    if (wu >= WU_TOTAL) return false;
    p = wu / (NXT * NYT);
    int rem = wu - p * (NXT * NYT);
    yt = rem / NXT;
    xt = rem - yt * NXT;
    return true;
}

__device__ __forceinline__ void vconv5(const unsigned short* __restrict__ Ap, int x4, int y0,
                                       const float* __restrict__ k1g, float4 acc[TV]) {
#pragma unroll
    for (int j = 0; j < TV; ++j) acc[j] = make_float4(0.f, 0.f, 0.f, 0.f);
    if (y0 >= R && y0 + TV - 1 + R < H) {
        const unsigned short* p = Ap + (size_t)(y0 - R) * W + x4;
#pragma unroll
        for (int u = 0; u < TV + 2 * R; ++u) {   // 55 rows
            ushort4 s = *(const ushort4*)p;
            p += W;
            float4 v = make_float4(bf2f(s.x), bf2f(s.y), bf2f(s.z), bf2f(s.w));
            const int jlo = (u - 2 * R > 0) ? u - 2 * R : 0;
            const int jhi = (u < TV - 1) ? u : TV - 1;
#pragma unroll
            for (int j = jlo; j <= jhi; ++j) {
                const float k = k1g[u - j];
                acc[j].x += k * v.x; acc[j].y += k * v.y;
                acc[j].z += k * v.z; acc[j].w += k * v.w;
            }
        }
    } else {
#pragma unroll
        for (int u = 0; u < TV + 2 * R; ++u) {
            int yy = reflect_idx(y0 - R + u, H);
            ushort4 s = *(const ushort4*)(Ap + (size_t)yy * W + x4);
            float4 v = make_float4(bf2f(s.x), bf2f(s.y), bf2f(s.z), bf2f(s.w));
            const int jlo = (u - 2 * R > 0) ? u - 2 * R : 0;
            const int jhi = (u < TV - 1) ? u : TV - 1;
#pragma unroll
            for (int j = jlo; j <= jhi; ++j) {
                const float k = k1g[u - j];
                acc[j].x += k * v.x; acc[j].y += k * v.y;
                acc[j].z += k * v.z; acc[j].w += k * v.w;
            }
        }
    }
}

__global__ __launch_bounds__(256, 8) void vblur_r(const unsigned short* __restrict__ A,
                                                  const float* __restrict__ img,
                                                  const float* __restrict__ k1g,
                                                  unsigned short* __restrict__ rbuf) {
    int p, yt, xt;
    if (!decode_wu(blockIdx.x, p, yt, xt)) return;
    const int tx = threadIdx.x & 31, ty = threadIdx.x >> 5;
    const int x4 = xt * 128 + tx * 4;
    const int y0 = yt * 40 + ty * TV;
    float4 acc[TV];
    vconv5(A + (size_t)p * PLANE, x4, y0, k1g, acc);
#pragma unroll
    for (int j = 0; j < TV; ++j) {
        size_t idx = (size_t)p * PLANE + (size_t)(y0 + j) * W + x4;
        float4 iv = *(const float4*)&img[idx];
        ushort4 rr;
        rr.x = f2bf(iv.x - acc[j].x);
        rr.y = f2bf(iv.y - acc[j].y);
        rr.z = f2bf(iv.z - acc[j].z);
        rr.w = f2bf(iv.w - acc[j].w);
        *(ushort4*)&rbuf[idx] = rr;
    }
}

__global__ __launch_bounds__(256, 8) void vblur_blend(const unsigned short* __restrict__ Bh,
                                                      const float* __restrict__ img,
                                                      const unsigned short* __restrict__ rbuf,
                                                      const float* __restrict__ k1g,
                                                      float* __restrict__ out) {
    int p, yt, xt;
    if (!decode_wu(blockIdx.x, p, yt, xt)) return;
    const int tx = threadIdx.x & 31, ty = threadIdx.x >> 5;
    const int x4 = xt * 128 + tx * 4;
    const int y0 = yt * 40 + ty * TV;
    float4 acc[TV];
    vconv5(Bh + (size_t)p * PLANE, x4, y0, k1g, acc);
#pragma unroll
    for (int j = 0; j < TV; ++j) {
        size_t idx = (size_t)p * PLANE + (size_t)(y0 + j) * W + x4;
        float4 iv = *(const float4*)&img[idx];
        ushort4 ru = *(const ushort4*)&rbuf[idx];
        float dx = fminf(fmaxf(iv.x + 0.5f * bf2f(ru.x), 0.f), 1.f) - iv.x;
        float dy = fminf(fmaxf(iv.y + 0.5f * bf2f(ru.y), 0.f), 1.f) - iv.y;
        float dz = fminf(fmaxf(iv.z + 0.5f * bf2f(ru.z), 0.f), 1.f) - iv.z;
        float dw = fminf(fmaxf(iv.w + 0.5f * bf2f(ru.w), 0.f), 1.f) - iv.w;
        float4 o;
        o.x = iv.x + acc[j].x * dx;
        o.y = iv.y + acc[j].y * dy;
        o.z = iv.z + acc[j].z * dz;
        o.w = iv.w + acc[j].w * dw;
        *(float4*)&out[idx] = o;
    }
}

extern "C" void kernel_launch(void* const* d_in, const int* in_sizes, int n_in,
                              void* d_out, int out_size, void* d_ws, size_t ws_size,
                              hipStream_t stream) {
    const float* img = (const float*)d_in[0];
    const float* k2d = (const float*)d_in[1];
    float* out = (float*)d_out;

    unsigned short* AB = (unsigned short*)d_ws;  // A, later Bh
    unsigned short* rbuf = AB + TOT;             // residual bf16
    float* k1 = (float*)(rbuf + TOT);

    const int gridHB = NBI + NBB;        // 6076
    const int gridVB = 8 * WU_PER_XCD;   // 2432

    hipLaunchKernelGGL(compute_k1, dim3(1), dim3(64), 0, stream, k2d, k1);
    hipLaunchKernelGGL((hblur8<false>), dim3(gridHB), dim3(256), 0, stream, (const void*)img, AB, k1);
    hipLaunchKernelGGL(vblur_r, dim3(gridVB), dim3(256), 0, stream, AB, img, k1, rbuf);
    hipLaunchKernelGGL((hblur8<true>), dim3(gridHB), dim3(256), 0, stream, (const void*)rbuf, AB, k1);
    hipLaunchKernelGGL(vblur_blend, dim3(gridVB), dim3(256), 0, stream, AB, img, rbuf, k1, out);
}